// Round 9
// baseline (614.705 us; speedup 1.0000x reference)
//
#include <hip/hip_runtime.h>
#include <math.h>
#include <stdint.h>

#define B_ 8
#define L_ 2048
#define D_ 256
#define NEG_INF_V (-1e10f)
#define NSTRIP 16

typedef __bf16 bf16x8 __attribute__((ext_vector_type(8)));
typedef float f32x4 __attribute__((ext_vector_type(4)));

#define MFMA16(a, b, c) __builtin_amdgcn_mfma_f32_16x16x32_bf16((a), (b), (c), 0, 0, 0)

// Fragment-major (FM) layout for a [rows x 256] bf16 matrix:
// granule index = ((G * 8 + kb) * 64 + q * 16 + m) ; granule = 16B = 8 bf16
// holds M[G*16 + m][kb*32 + q*8 .. +8).  G = absolute row/16.
// A wave (lane = q*16+m) loads frag (G_tile, kb) as one coalesced 1KB segment.

// ---------- K0: fp32 -> bf16 FM transform + row sumsq + W FM + counter init ----------
__global__ __launch_bounds__(256) void convert_kernel(
    const float* __restrict__ x, const float* __restrict__ y,
    const float* __restrict__ W,
    __bf16* __restrict__ srcFM, __bf16* __restrict__ predFM,
    __bf16* __restrict__ WFM,
    float* __restrict__ src_sq, float* __restrict__ pred_sq,
    float* __restrict__ Sarr, unsigned int* __restrict__ gcnt,
    unsigned int* __restrict__ tileCnt) {
    int tid = threadIdx.x;
    int blk = blockIdx.x;
    if (blk < 2048) {
        const float* in = (blk < 1024) ? x : y;
        __bf16* out = (blk < 1024) ? srcFM : predFM;
        float* sqout = (blk < 1024) ? src_sq : pred_sq;
        int g = blk & 1023;  // row-group (16 rows)
        __shared__ __align__(16) __bf16 sFM[512 * 8];
        __shared__ float sSQ[16];
        int kb = (tid & 31) >> 2, qq = tid & 3;
        #pragma unroll
        for (int pass = 0; pass < 2; ++pass) {
            int m = pass * 8 + (tid >> 5);
            const float* p = in + ((size_t)g * 16 + m) * D_ + (tid & 31) * 8;
            float4 v0 = *(const float4*)p;
            float4 v1 = *(const float4*)(p + 4);
            float ss = v0.x * v0.x + v0.y * v0.y + v0.z * v0.z + v0.w * v0.w +
                       v1.x * v1.x + v1.y * v1.y + v1.z * v1.z + v1.w * v1.w;
            #pragma unroll
            for (int o = 16; o > 0; o >>= 1) ss += __shfl_xor(ss, o, 64);
            if ((tid & 31) == 0) sSQ[m] = ss;
            union { __bf16 o[8]; bf16x8 v; } cv;
            cv.o[0] = (__bf16)v0.x; cv.o[1] = (__bf16)v0.y;
            cv.o[2] = (__bf16)v0.z; cv.o[3] = (__bf16)v0.w;
            cv.o[4] = (__bf16)v1.x; cv.o[5] = (__bf16)v1.y;
            cv.o[6] = (__bf16)v1.z; cv.o[7] = (__bf16)v1.w;
            *(bf16x8*)(sFM + (m * 32 + kb * 4 + qq) * 8) = cv.v;
        }
        __syncthreads();
        int G0 = tid * 2;
        int kb0 = G0 >> 6, q0 = (G0 >> 4) & 3, m0 = G0 & 15;
        bf16x8 a = *(const bf16x8*)(sFM + (m0 * 32 + kb0 * 4 + q0) * 8);
        bf16x8 bgr = *(const bf16x8*)(sFM + ((m0 + 1) * 32 + kb0 * 4 + q0) * 8);
        *(bf16x8*)(out + ((size_t)g * 512 + G0) * 8) = a;
        *(bf16x8*)(out + ((size_t)g * 512 + G0 + 1) * 8) = bgr;
        if (tid < 16) sqout[g * 16 + tid] = sSQ[tid];
    } else {
        if (blk == 2048) {  // zero the cross-kernel accumulators (stream-ordered)
            tileCnt[tid] = 0u;
            if (tid < 24) Sarr[tid] = 0.f;
            if (tid == 255) *gcnt = 0u;
        }
        int idx = (blk - 2048) * 256 + tid;
        int m = idx & 15, q = (idx >> 4) & 3, kb = (idx >> 6) & 7, gn = idx >> 9;
        union { __bf16 o[8]; bf16x8 v; } cv;
        #pragma unroll
        for (int j = 0; j < 8; ++j)
            cv.o[j] = (__bf16)W[(size_t)(kb * 32 + q * 8 + j) * D_ + gn * 16 + m];
        *(bf16x8*)(WFM + (size_t)idx * 8) = cv.v;
    }
}

// ---------- K1: predW = pred x W, FM in / FM out (XCD-swizzled) ----------
__global__ __launch_bounds__(256, 2) void predw_mfma(
    const __bf16* __restrict__ predFM, const __bf16* __restrict__ WFM,
    const float* __restrict__ pred_mask, __bf16* __restrict__ pwFM) {
    __shared__ __align__(16) __bf16 sT[128 * 136];
    __shared__ int flag;
    int tid = threadIdx.x, lane = tid & 63, wid = tid >> 6;
    int wp = wid >> 1, wn = wid & 1;
    int id = blockIdx.x;
    int m0 = (((id >> 3) & 15) + (id & 7) * 16) * 128;
    int n0 = (id >> 7) * 128;
    if (tid == 0) flag = 0;
    __syncthreads();
    if (tid < 128) { if (pred_mask[m0 + tid] != 0.f) atomicOr(&flag, 1); }
    __syncthreads();
    if (!flag) return;

    const __bf16* bA = predFM + (size_t)(m0 / 16 + wp * 4) * 4096 + lane * 8;
    const __bf16* bB = WFM + (size_t)(n0 / 16 + wn * 4) * 4096 + lane * 8;
    f32x4 acc[4][4] = {};
    #pragma unroll
    for (int kb = 0; kb < 8; ++kb) {
        bf16x8 fA[4], fB[4];
        #pragma unroll
        for (int t = 0; t < 4; ++t) {
            fA[t] = *(const bf16x8*)(bA + (t * 8 + kb) * 512);
            fB[t] = *(const bf16x8*)(bB + (t * 8 + kb) * 512);
        }
        #pragma unroll
        for (int pt = 0; pt < 4; ++pt)
            #pragma unroll
            for (int st = 0; st < 4; ++st)
                acc[pt][st] = MFMA16(fA[pt], fB[st], acc[pt][st]);
    }
    int q = lane >> 4, cn = lane & 15;
    #pragma unroll
    for (int pt = 0; pt < 4; ++pt)
        #pragma unroll
        for (int st = 0; st < 4; ++st)
            #pragma unroll
            for (int r = 0; r < 4; ++r)
                sT[(wp * 64 + pt * 16 + q * 4 + r) * 136 + wn * 64 + st * 16 + cn] =
                    (__bf16)acc[pt][st][r];
    __syncthreads();
    #pragma unroll
    for (int i = 0; i < 8; ++i) {
        int idx = i * 256 + tid;
        int gl = idx >> 8, kbl = (idx >> 6) & 3, qq = (idx >> 4) & 3, mm = idx & 15;
        bf16x8 v = *(const bf16x8*)(sT + (gl * 16 + mm) * 136 + kbl * 32 + qq * 8);
        *(bf16x8*)(pwFM +
                   (((size_t)(m0 / 16 + gl) * 8 + n0 / 32 + kbl) * 64 + qq * 16 + mm) * 8) = v;
    }
}

// ---------- K2: fused T/G MFMA + in-kernel combine via last-arrival ----------
// wave wid computes BOTH aT (pwFM.src^T) and aG (predFM.src^T) for its 16 rows;
// the 16th sy-block to finish a (b,px) tile combines its 64 rows; the 256th
// tile-owner computes the final scalar.  grid 4096: id = b + 8*px + 256*sy.
__global__ __launch_bounds__(256, 3) void fused_mfma(
    const __bf16* __restrict__ srcFM, const __bf16* __restrict__ predFM,
    const __bf16* __restrict__ pwFM,
    const float* __restrict__ src_mask, const float* __restrict__ pred_mask,
    const float* __restrict__ src_sq, const float* __restrict__ pred_sq,
    float* __restrict__ m_part, float* __restrict__ l_part,
    float* __restrict__ w_part, float* __restrict__ Sarr,
    unsigned int* __restrict__ gcnt, unsigned int* __restrict__ tileCnt,
    float* __restrict__ out) {
    __shared__ float sPM[64], sPSQ[64], sSM[128], sSSQ[128];
    __shared__ int flg[4];  // 0 anyValidP, 1 anyInvalidP, 2 anyValidS, 3 anyInvalidS
    __shared__ int sOwn;
    int tid = threadIdx.x, lane = tid & 63, wid = tid >> 6;
    int id = blockIdx.x;
    int b = id & 7, px = (id >> 3) & 31, sy = id >> 8;
    int p0 = px * 64;

    if (tid < 4) flg[tid] = 0;
    __syncthreads();
    if (tid < 64) {
        float v = pred_mask[b * L_ + p0 + tid];
        sPM[tid] = v;
        sPSQ[tid] = pred_sq[b * L_ + p0 + tid];
        atomicOr(&flg[(v != 0.f) ? 0 : 1], 1);
    } else if (tid < 192) {
        int t = tid - 64;
        float v = src_mask[b * L_ + sy * 128 + t];
        sSM[t] = v;
        sSSQ[t] = src_sq[b * L_ + sy * 128 + t];
        atomicOr(&flg[(v != 0.f) ? 2 : 3], 1);
    }
    __syncthreads();
    const bool anyVP = flg[0] != 0, anyIP = flg[1] != 0, anyVS = flg[2] != 0;
    const bool doT = anyVP && anyVS;
    const bool doG = anyVS || anyIP;
    if (!doG) {
        // all p valid & all s masked: strip is zero-weighted vs any real strip
        if (tid < 64) {
            size_t o = ((size_t)(b * L_ + p0 + tid)) * NSTRIP + sy;
            m_part[o] = NEG_INF_V; l_part[o] = 128.f; w_part[o] = 0.f;
        }
    } else {
        const __bf16* bS = srcFM + ((size_t)(b * 128 + sy * 8)) * 4096 + lane * 8;
        const __bf16* bP = predFM + ((size_t)(b * 128 + px * 4 + wid)) * 4096 + lane * 8;
        const __bf16* bW = pwFM + ((size_t)(b * 128 + px * 4 + wid)) * 4096 + lane * 8;

        f32x4 aT[8] = {};
        f32x4 aG[8] = {};
        if (doT) {
            #pragma unroll
            for (int kb = 0; kb < 8; ++kb) {
                bf16x8 fP = *(const bf16x8*)(bP + kb * 512);
                bf16x8 fW = *(const bf16x8*)(bW + kb * 512);
                bf16x8 fB[8];
                #pragma unroll
                for (int t = 0; t < 8; ++t)
                    fB[t] = *(const bf16x8*)(bS + (t * 8 + kb) * 512);
                #pragma unroll
                for (int t = 0; t < 8; ++t) {
                    aG[t] = MFMA16(fP, fB[t], aG[t]);
                    aT[t] = MFMA16(fW, fB[t], aT[t]);
                }
            }
        } else {
            #pragma unroll
            for (int kb = 0; kb < 8; ++kb) {
                bf16x8 fP = *(const bf16x8*)(bP + kb * 512);
                bf16x8 fB[8];
                #pragma unroll
                for (int t = 0; t < 8; ++t)
                    fB[t] = *(const bf16x8*)(bS + (t * 8 + kb) * 512);
                #pragma unroll
                for (int t = 0; t < 8; ++t)
                    aG[t] = MFMA16(fP, fB[t], aG[t]);
            }
        }

        // epilogue: element (row = wid*16 + q*4 + r, col = t*16 + cn) = a[t][r]
        int q = lane >> 4, cn = lane & 15;
        float smv[8], sqv[8];
        #pragma unroll
        for (int t = 0; t < 8; ++t) {
            smv[t] = sSM[t * 16 + cn];
            sqv[t] = sSSQ[t * 16 + cn];
        }
        int rbase = wid * 16 + q * 4;
        #pragma unroll
        for (int r = 0; r < 4; ++r) {
            float pm = sPM[rbase + r], psq = sPSQ[rbase + r];
            float tv[8], cst[8];
            float tm = -1e30f;
            #pragma unroll
            for (int t = 0; t < 8; ++t) {
                cst[t] = __builtin_amdgcn_sqrtf(
                    fmaxf(psq + sqv[t] - 2.f * aG[t][r], 0.f));
                float tt = doT ? aT[t][r] : NEG_INF_V;
                // pm==0: uniform row (tv=0 everywhere -> e=1, l=128, w=sum cost)
                tv[t] = (pm == 0.f) ? 0.f : (smv[t] != 0.f ? tt : NEG_INF_V);
                tm = fmaxf(tm, tv[t]);
            }
            #pragma unroll
            for (int o = 8; o > 0; o >>= 1) tm = fmaxf(tm, __shfl_xor(tm, o, 16));
            float l = 0.f, w = 0.f;
            #pragma unroll
            for (int t = 0; t < 8; ++t) {
                float e = __expf(tv[t] - tm);
                l += e;
                w = fmaf(e, cst[t], w);
            }
            #pragma unroll
            for (int o = 8; o > 0; o >>= 1) {
                l += __shfl_xor(l, o, 16);
                w += __shfl_xor(w, o, 16);
            }
            if (cn == 0) {
                size_t o = ((size_t)(b * L_ + p0 + rbase + r)) * NSTRIP + sy;
                m_part[o] = tm;
                l_part[o] = l;
                w_part[o] = w;
            }
        }
    }

    // ---- arrival: 16th block of (b,px) combines the tile's 64 rows ----
    __threadfence();  // release this block's partial writes (all writer threads)
    __syncthreads();
    if (tid == 0)
        sOwn = (atomicAdd(&tileCnt[b * 32 + px], 1u) == 15u) ? 1 : 0;
    __syncthreads();
    if (!sOwn) return;
    __threadfence();  // acquire other blocks' partials

    float sv = 0.f, n1 = 0.f, n2 = 0.f;
    if (wid == 0) {
        int rr = b * L_ + p0 + lane;
        size_t base = (size_t)rr * NSTRIP;
        float mm = -1e30f;
        #pragma unroll
        for (int s = 0; s < NSTRIP; ++s) mm = fmaxf(mm, m_part[base + s]);
        float l = 0.f, w = 0.f;
        #pragma unroll
        for (int s = 0; s < NSTRIP; ++s) {
            float e = __expf(m_part[base + s] - mm);
            l = fmaf(l_part[base + s], e, l);
            w = fmaf(w_part[base + s], e, w);
        }
        sv = w / l;
        n1 = pred_mask[rr];
        n2 = src_mask[rr];
        #pragma unroll
        for (int o = 32; o > 0; o >>= 1) {
            sv += __shfl_xor(sv, o, 64);
            n1 += __shfl_xor(n1, o, 64);
            n2 += __shfl_xor(n2, o, 64);
        }
        if (lane == 0) {
            atomicAdd(&Sarr[b], sv);
            atomicAdd(&Sarr[8 + b], n1);
            atomicAdd(&Sarr[16 + b], n2);
            __threadfence();
            if (atomicAdd(gcnt, 1u) == 255u) {  // final tile-owner
                __threadfence();
                float fb[24];
                for (int i = 0; i < 24; ++i) fb[i] = atomicAdd(&Sarr[i], 0.f);
                float ss = 0.f, si = 0.f;
                for (int bb = 0; bb < B_; bb++) {
                    ss += fb[bb];
                    si += 1.0f / (fb[8 + bb] * fb[16 + bb]);
                }
                out[0] = ss * si / (float)(B_ * B_);  // LAMBDA_W = 1.0
            }
        }
    }
}

extern "C" void kernel_launch(void* const* d_in, const int* in_sizes, int n_in,
                              void* d_out, int out_size, void* d_ws, size_t ws_size,
                              hipStream_t stream) {
    const float* h_x = (const float*)d_in[0];     // src
    const float* h_y = (const float*)d_in[1];     // pred
    const float* x_mask = (const float*)d_in[2];  // src_mask
    const float* y_mask = (const float*)d_in[3];  // pred_mask
    const float* W = (const float*)d_in[4];

    char* w8 = (char*)d_ws;
    const size_t BLD2 = (size_t)B_ * L_ * D_ * 2;  // 8 MB
    __bf16* srcFM = (__bf16*)w8;
    __bf16* predFM = (__bf16*)(w8 + BLD2);
    __bf16* pwFM = (__bf16*)(w8 + 2 * BLD2);
    __bf16* WFM = (__bf16*)(w8 + 3 * BLD2);                   // 128 KB
    float* src_sq = (float*)(w8 + 3 * BLD2 + (1 << 17));      // 64 KB
    float* pred_sq = (float*)(w8 + 3 * BLD2 + (1 << 17) + (1 << 16));
    char* pbase = w8 + 3 * BLD2 + (1 << 17) + (1 << 17);
    const size_t PSZ = (size_t)B_ * L_ * NSTRIP * 4;          // 1 MB each
    float* m_part = (float*)pbase;
    float* l_part = (float*)(pbase + PSZ);
    float* w_part = (float*)(pbase + 2 * PSZ);
    float* Sarr = (float*)(pbase + 3 * PSZ);                  // 24 floats
    unsigned int* gcnt = (unsigned int*)(pbase + 3 * PSZ + 128);
    unsigned int* tileCnt = (unsigned int*)(pbase + 3 * PSZ + 256);  // 256 u32

    convert_kernel<<<2080, 256, 0, stream>>>(h_x, h_y, W, srcFM, predFM, WFM,
                                             src_sq, pred_sq, Sarr, gcnt, tileCnt);
    predw_mfma<<<256, 256, 0, stream>>>(predFM, WFM, y_mask, pwFM);
    fused_mfma<<<4096, 256, 0, stream>>>(
        srcFM, predFM, pwFM, x_mask, y_mask, src_sq, pred_sq,
        m_part, l_part, w_part, Sarr, gcnt, tileCnt, (float*)d_out);
}

// Round 10
// 147.682 us; speedup vs baseline: 4.1624x; 4.1624x over previous
//
#include <hip/hip_runtime.h>
#include <math.h>
#include <stdint.h>

#define B_ 8
#define L_ 2048
#define D_ 256
#define NEG_INF_V (-1e10f)
#define NSTRIP 32

typedef __bf16 bf16x8 __attribute__((ext_vector_type(8)));
typedef float f32x4 __attribute__((ext_vector_type(4)));

#define MFMA16(a, b, c) __builtin_amdgcn_mfma_f32_16x16x32_bf16((a), (b), (c), 0, 0, 0)

// Fragment-major (FM) layout for a [rows x 256] bf16 matrix:
// granule index = ((G * 8 + kb) * 64 + q * 16 + m) ; granule = 16B = 8 bf16
// holds M[G*16 + m][kb*32 + q*8 .. +8).  G = absolute row/16.
// A wave (lane = q*16+m) loads frag (G_tile, kb) as one coalesced 1KB segment.

// ---------- K0: fp32 -> bf16 FM transform (coalesced) + row sumsq + W FM ----------
__global__ __launch_bounds__(256) void convert_kernel(
    const float* __restrict__ x, const float* __restrict__ y,
    const float* __restrict__ W,
    __bf16* __restrict__ srcFM, __bf16* __restrict__ predFM,
    __bf16* __restrict__ WFM,
    float* __restrict__ src_sq, float* __restrict__ pred_sq) {
    int tid = threadIdx.x;
    int blk = blockIdx.x;
    if (blk < 2048) {
        const float* in = (blk < 1024) ? x : y;
        __bf16* out = (blk < 1024) ? srcFM : predFM;
        float* sqout = (blk < 1024) ? src_sq : pred_sq;
        int g = blk & 1023;  // row-group (16 rows)
        __shared__ __align__(16) __bf16 sFM[512 * 8];
        __shared__ float sSQ[16];
        int kb = (tid & 31) >> 2, qq = tid & 3;
        #pragma unroll
        for (int pass = 0; pass < 2; ++pass) {
            int m = pass * 8 + (tid >> 5);
            const float* p = in + ((size_t)g * 16 + m) * D_ + (tid & 31) * 8;
            float4 v0 = *(const float4*)p;
            float4 v1 = *(const float4*)(p + 4);
            float ss = v0.x * v0.x + v0.y * v0.y + v0.z * v0.z + v0.w * v0.w +
                       v1.x * v1.x + v1.y * v1.y + v1.z * v1.z + v1.w * v1.w;
            #pragma unroll
            for (int o = 16; o > 0; o >>= 1) ss += __shfl_xor(ss, o, 64);
            if ((tid & 31) == 0) sSQ[m] = ss;
            union { __bf16 o[8]; bf16x8 v; } cv;
            cv.o[0] = (__bf16)v0.x; cv.o[1] = (__bf16)v0.y;
            cv.o[2] = (__bf16)v0.z; cv.o[3] = (__bf16)v0.w;
            cv.o[4] = (__bf16)v1.x; cv.o[5] = (__bf16)v1.y;
            cv.o[6] = (__bf16)v1.z; cv.o[7] = (__bf16)v1.w;
            *(bf16x8*)(sFM + (m * 32 + kb * 4 + qq) * 8) = cv.v;
        }
        __syncthreads();
        int G0 = tid * 2;
        int kb0 = G0 >> 6, q0 = (G0 >> 4) & 3, m0 = G0 & 15;
        bf16x8 a = *(const bf16x8*)(sFM + (m0 * 32 + kb0 * 4 + q0) * 8);
        bf16x8 bgr = *(const bf16x8*)(sFM + ((m0 + 1) * 32 + kb0 * 4 + q0) * 8);
        *(bf16x8*)(out + ((size_t)g * 512 + G0) * 8) = a;
        *(bf16x8*)(out + ((size_t)g * 512 + G0 + 1) * 8) = bgr;
        if (tid < 16) sqout[g * 16 + tid] = sSQ[tid];
    } else {
        int idx = (blk - 2048) * 256 + tid;
        int m = idx & 15, q = (idx >> 4) & 3, kb = (idx >> 6) & 7, gn = idx >> 9;
        union { __bf16 o[8]; bf16x8 v; } cv;
        #pragma unroll
        for (int j = 0; j < 8; ++j)
            cv.o[j] = (__bf16)W[(size_t)(kb * 32 + q * 8 + j) * D_ + gn * 16 + m];
        *(bf16x8*)(WFM + (size_t)idx * 8) = cv.v;
    }
}

// ---------- K1: predW = pred x W, FM in / FM out (XCD-swizzled) ----------
__global__ __launch_bounds__(256, 2) void predw_mfma(
    const __bf16* __restrict__ predFM, const __bf16* __restrict__ WFM,
    const float* __restrict__ pred_mask, __bf16* __restrict__ pwFM) {
    __shared__ __align__(16) __bf16 sT[128 * 136];
    __shared__ int flag;
    int tid = threadIdx.x, lane = tid & 63, wid = tid >> 6;
    int wp = wid >> 1, wn = wid & 1;
    int id = blockIdx.x;
    int m0 = (((id >> 3) & 15) + (id & 7) * 16) * 128;
    int n0 = (id >> 7) * 128;
    if (tid == 0) flag = 0;
    __syncthreads();
    if (tid < 128) { if (pred_mask[m0 + tid] != 0.f) atomicOr(&flag, 1); }
    __syncthreads();
    if (!flag) return;

    const __bf16* bA = predFM + (size_t)(m0 / 16 + wp * 4) * 4096 + lane * 8;
    const __bf16* bB = WFM + (size_t)(n0 / 16 + wn * 4) * 4096 + lane * 8;
    f32x4 acc[4][4] = {};
    #pragma unroll
    for (int kb = 0; kb < 8; ++kb) {
        bf16x8 fA[4], fB[4];
        #pragma unroll
        for (int t = 0; t < 4; ++t) {
            fA[t] = *(const bf16x8*)(bA + (t * 8 + kb) * 512);
            fB[t] = *(const bf16x8*)(bB + (t * 8 + kb) * 512);
        }
        #pragma unroll
        for (int pt = 0; pt < 4; ++pt)
            #pragma unroll
            for (int st = 0; st < 4; ++st)
                acc[pt][st] = MFMA16(fA[pt], fB[st], acc[pt][st]);
    }
    int q = lane >> 4, cn = lane & 15;
    #pragma unroll
    for (int pt = 0; pt < 4; ++pt)
        #pragma unroll
        for (int st = 0; st < 4; ++st)
            #pragma unroll
            for (int r = 0; r < 4; ++r)
                sT[(wp * 64 + pt * 16 + q * 4 + r) * 136 + wn * 64 + st * 16 + cn] =
                    (__bf16)acc[pt][st][r];
    __syncthreads();
    #pragma unroll
    for (int i = 0; i < 8; ++i) {
        int idx = i * 256 + tid;
        int gl = idx >> 8, kbl = (idx >> 6) & 3, qq = (idx >> 4) & 3, mm = idx & 15;
        bf16x8 v = *(const bf16x8*)(sT + (gl * 16 + mm) * 136 + kbl * 32 + qq * 8);
        *(bf16x8*)(pwFM +
                   (((size_t)(m0 / 16 + gl) * 8 + n0 / 32 + kbl) * 64 + qq * 16 + mm) * 8) = v;
    }
}

// ---------- K2: fused T/G MFMA, 64p x 64s tiles, 32-AGPR waves, high occupancy ----------
// wave wid owns rows [wid*16, wid*16+16) x all 64 cols; computes BOTH aT and aG;
// epilogue reads T/G straight from the wave's own AGPRs.
// grid 8192: id = b + 8*px + 256*sy  (id&7 locks batch to XCD)
__global__ __launch_bounds__(256, 4) void fused_mfma(
    const __bf16* __restrict__ srcFM, const __bf16* __restrict__ predFM,
    const __bf16* __restrict__ pwFM,
    const float* __restrict__ src_mask, const float* __restrict__ pred_mask,
    const float* __restrict__ src_sq, const float* __restrict__ pred_sq,
    float* __restrict__ m_part, float* __restrict__ l_part,
    float* __restrict__ w_part, float* __restrict__ Sarr,
    unsigned int* __restrict__ counter) {
    __shared__ float sPM[64], sPSQ[64], sSM[64], sSSQ[64];
    __shared__ int flg[4];  // 0 anyValidP, 1 anyInvalidP, 2 anyValidS, 3 anyInvalidS
    int tid = threadIdx.x, lane = tid & 63, wid = tid >> 6;
    int id = blockIdx.x;
    int b = id & 7, px = (id >> 3) & 31, sy = id >> 8;  // sy 0..31
    int p0 = px * 64;

    if (id == 0) {  // init cross-kernel accumulators for combine (runs after us)
        if (tid == 0) *counter = 0u;
        if (tid < 24) Sarr[tid] = 0.f;
    }
    if (tid < 4) flg[tid] = 0;
    __syncthreads();
    if (tid < 64) {
        float v = pred_mask[b * L_ + p0 + tid];
        sPM[tid] = v;
        sPSQ[tid] = pred_sq[b * L_ + p0 + tid];
        atomicOr(&flg[(v != 0.f) ? 0 : 1], 1);
    } else if (tid < 128) {
        int t = tid - 64;
        float v = src_mask[b * L_ + sy * 64 + t];
        sSM[t] = v;
        sSSQ[t] = src_sq[b * L_ + sy * 64 + t];
        atomicOr(&flg[(v != 0.f) ? 2 : 3], 1);
    }
    __syncthreads();
    const bool anyVP = flg[0] != 0, anyIP = flg[1] != 0, anyVS = flg[2] != 0;
    const bool doT = anyVP && anyVS;
    const bool doG = anyVS || anyIP;
    if (!doG) {
        // all p valid & all s masked: strip is zero-weighted vs any real strip
        if (tid < 64) {
            size_t o = ((size_t)(b * L_ + p0 + tid)) * NSTRIP + sy;
            m_part[o] = NEG_INF_V; l_part[o] = 64.f; w_part[o] = 0.f;
        }
        return;
    }

    const __bf16* bS = srcFM + ((size_t)(b * 128 + sy * 4)) * 4096 + lane * 8;
    const __bf16* bP = predFM + ((size_t)(b * 128 + px * 4 + wid)) * 4096 + lane * 8;
    const __bf16* bW = pwFM + ((size_t)(b * 128 + px * 4 + wid)) * 4096 + lane * 8;

    f32x4 aT[4] = {};
    f32x4 aG[4] = {};
    if (doT) {
        #pragma unroll
        for (int kb = 0; kb < 8; ++kb) {
            bf16x8 fP = *(const bf16x8*)(bP + kb * 512);
            bf16x8 fW = *(const bf16x8*)(bW + kb * 512);
            bf16x8 fB[4];
            #pragma unroll
            for (int t = 0; t < 4; ++t)
                fB[t] = *(const bf16x8*)(bS + (t * 8 + kb) * 512);
            #pragma unroll
            for (int t = 0; t < 4; ++t) {
                aG[t] = MFMA16(fP, fB[t], aG[t]);
                aT[t] = MFMA16(fW, fB[t], aT[t]);
            }
        }
    } else {
        #pragma unroll
        for (int kb = 0; kb < 8; ++kb) {
            bf16x8 fP = *(const bf16x8*)(bP + kb * 512);
            bf16x8 fB[4];
            #pragma unroll
            for (int t = 0; t < 4; ++t)
                fB[t] = *(const bf16x8*)(bS + (t * 8 + kb) * 512);
            #pragma unroll
            for (int t = 0; t < 4; ++t)
                aG[t] = MFMA16(fP, fB[t], aG[t]);
        }
    }

    // epilogue: element (row = wid*16 + q*4 + r, col = t*16 + cn) = a[t][r]
    int q = lane >> 4, cn = lane & 15;
    float smv[4], sqv[4];
    #pragma unroll
    for (int t = 0; t < 4; ++t) {
        smv[t] = sSM[t * 16 + cn];
        sqv[t] = sSSQ[t * 16 + cn];
    }
    int rbase = wid * 16 + q * 4;
    #pragma unroll
    for (int r = 0; r < 4; ++r) {
        float pm = sPM[rbase + r], psq = sPSQ[rbase + r];
        float tv[4], cst[4];
        float tm = -1e30f;
        #pragma unroll
        for (int t = 0; t < 4; ++t) {
            cst[t] = __builtin_amdgcn_sqrtf(
                fmaxf(psq + sqv[t] - 2.f * aG[t][r], 0.f));
            float tt = doT ? aT[t][r] : NEG_INF_V;
            // pm==0: uniform row (tv=0 everywhere -> e=1, l=64, w=sum cost)
            tv[t] = (pm == 0.f) ? 0.f : (smv[t] != 0.f ? tt : NEG_INF_V);
            tm = fmaxf(tm, tv[t]);
        }
        #pragma unroll
        for (int o = 8; o > 0; o >>= 1) tm = fmaxf(tm, __shfl_xor(tm, o, 16));
        float l = 0.f, w = 0.f;
        #pragma unroll
        for (int t = 0; t < 4; ++t) {
            float e = __expf(tv[t] - tm);
            l += e;
            w = fmaf(e, cst[t], w);
        }
        #pragma unroll
        for (int o = 8; o > 0; o >>= 1) {
            l += __shfl_xor(l, o, 16);
            w += __shfl_xor(w, o, 16);
        }
        if (cn == 0) {
            size_t o = ((size_t)(b * L_ + p0 + rbase + r)) * NSTRIP + sy;
            m_part[o] = tm;
            l_part[o] = l;
            w_part[o] = w;
        }
    }
}

// ---------- K3: combine strips -> per-batch atomic sums; last block finalizes ----------
__global__ __launch_bounds__(256) void combine_kernel(
    const float* __restrict__ m_part, const float* __restrict__ l_part,
    const float* __restrict__ w_part,
    const float* __restrict__ x_mask, const float* __restrict__ y_mask,
    float* __restrict__ Sarr, unsigned int* __restrict__ counter,
    float* __restrict__ out) {
    int tid = threadIdx.x;
    int r = blockIdx.x * 256 + tid;  // 64 blocks, 8 per batch
    int b = r >> 11;
    size_t base = (size_t)r * NSTRIP;
    float mm = -1e30f;
    #pragma unroll
    for (int s = 0; s < NSTRIP; ++s) mm = fmaxf(mm, m_part[base + s]);
    float l = 0.f, w = 0.f;
    #pragma unroll
    for (int s = 0; s < NSTRIP; ++s) {
        float e = __expf(m_part[base + s] - mm);
        l = fmaf(l_part[base + s], e, l);
        w = fmaf(w_part[base + s], e, w);
    }
    float sv = w / l;
    float n1 = y_mask[r], n2 = x_mask[r];
    __shared__ float red[3][256];
    red[0][tid] = sv; red[1][tid] = n1; red[2][tid] = n2;
    __syncthreads();
    for (int o = 128; o > 0; o >>= 1) {
        if (tid < o) {
            red[0][tid] += red[0][tid + o];
            red[1][tid] += red[1][tid + o];
            red[2][tid] += red[2][tid + o];
        }
        __syncthreads();
    }
    __shared__ int isLast;
    if (tid == 0) {
        atomicAdd(&Sarr[b], red[0][0]);
        atomicAdd(&Sarr[8 + b], red[1][0]);
        atomicAdd(&Sarr[16 + b], red[2][0]);
        __threadfence();
        isLast = (atomicAdd(counter, 1u) == 63u) ? 1 : 0;
    }
    __syncthreads();
    if (isLast) {
        __shared__ float fb[24];
        if (tid < 24) fb[tid] = atomicAdd(&Sarr[tid], 0.f);  // coherent read
        __syncthreads();
        if (tid == 0) {
            float ss = 0.f, si = 0.f;
            for (int bb = 0; bb < B_; bb++) {
                ss += fb[bb];
                si += 1.0f / (fb[8 + bb] * fb[16 + bb]);
            }
            out[0] = ss * si / (float)(B_ * B_);  // LAMBDA_W = 1.0
        }
    }
}

extern "C" void kernel_launch(void* const* d_in, const int* in_sizes, int n_in,
                              void* d_out, int out_size, void* d_ws, size_t ws_size,
                              hipStream_t stream) {
    const float* h_x = (const float*)d_in[0];     // src
    const float* h_y = (const float*)d_in[1];     // pred
    const float* x_mask = (const float*)d_in[2];  // src_mask
    const float* y_mask = (const float*)d_in[3];  // pred_mask
    const float* W = (const float*)d_in[4];

    char* w8 = (char*)d_ws;
    const size_t BLD2 = (size_t)B_ * L_ * D_ * 2;  // 8 MB
    __bf16* srcFM = (__bf16*)w8;
    __bf16* predFM = (__bf16*)(w8 + BLD2);
    __bf16* pwFM = (__bf16*)(w8 + 2 * BLD2);
    __bf16* WFM = (__bf16*)(w8 + 3 * BLD2);                   // 128 KB
    float* src_sq = (float*)(w8 + 3 * BLD2 + (1 << 17));      // 64 KB
    float* pred_sq = (float*)(w8 + 3 * BLD2 + (1 << 17) + (1 << 16));
    char* pbase = w8 + 3 * BLD2 + (1 << 17) + (1 << 17);
    const size_t PSZ = (size_t)B_ * L_ * NSTRIP * 4;          // 2 MB each
    float* m_part = (float*)pbase;
    float* l_part = (float*)(pbase + PSZ);
    float* w_part = (float*)(pbase + 2 * PSZ);
    float* Sarr = (float*)(pbase + 3 * PSZ);                  // 24 floats
    unsigned int* counter = (unsigned int*)(pbase + 3 * PSZ + 128);

    convert_kernel<<<2080, 256, 0, stream>>>(h_x, h_y, W, srcFM, predFM, WFM,
                                             src_sq, pred_sq);
    predw_mfma<<<256, 256, 0, stream>>>(predFM, WFM, y_mask, pwFM);
    fused_mfma<<<8192, 256, 0, stream>>>(
        srcFM, predFM, pwFM, x_mask, y_mask, src_sq, pred_sq,
        m_part, l_part, w_part, Sarr, counter);
    combine_kernel<<<B_ * L_ / 256, 256, 0, stream>>>(
        m_part, l_part, w_part, x_mask, y_mask, Sarr, counter, (float*)d_out);
}

// Round 11
// 146.366 us; speedup vs baseline: 4.1998x; 1.0090x over previous
//
#include <hip/hip_runtime.h>
#include <math.h>
#include <stdint.h>

#define B_ 8
#define L_ 2048
#define D_ 256
#define NEG_INF_V (-1e10f)
#define NSTRIP 32

typedef __bf16 bf16x8 __attribute__((ext_vector_type(8)));
typedef float f32x4 __attribute__((ext_vector_type(4)));

#define MFMA16(a, b, c) __builtin_amdgcn_mfma_f32_16x16x32_bf16((a), (b), (c), 0, 0, 0)

// Fragment-major (FM) layout for a [rows x 256] bf16 matrix:
// granule index = ((G * 8 + kb) * 64 + q * 16 + m) ; granule = 16B = 8 bf16
// holds M[G*16 + m][kb*32 + q*8 .. +8).  G = absolute row/16.
// A wave (lane = q*16+m) loads frag (G_tile, kb) as one coalesced 1KB segment.

// ---------- K0: fp32 -> bf16 FM transform (coalesced) + row sumsq + W FM ----------
__global__ __launch_bounds__(256) void convert_kernel(
    const float* __restrict__ x, const float* __restrict__ y,
    const float* __restrict__ W,
    __bf16* __restrict__ srcFM, __bf16* __restrict__ predFM,
    __bf16* __restrict__ WFM,
    float* __restrict__ src_sq, float* __restrict__ pred_sq) {
    int tid = threadIdx.x;
    int blk = blockIdx.x;
    if (blk < 2048) {
        const float* in = (blk < 1024) ? x : y;
        __bf16* out = (blk < 1024) ? srcFM : predFM;
        float* sqout = (blk < 1024) ? src_sq : pred_sq;
        int g = blk & 1023;  // row-group (16 rows)
        __shared__ __align__(16) __bf16 sFM[512 * 8];
        __shared__ float sSQ[16];
        int kb = (tid & 31) >> 2, qq = tid & 3;
        #pragma unroll
        for (int pass = 0; pass < 2; ++pass) {
            int m = pass * 8 + (tid >> 5);
            const float* p = in + ((size_t)g * 16 + m) * D_ + (tid & 31) * 8;
            float4 v0 = *(const float4*)p;
            float4 v1 = *(const float4*)(p + 4);
            float ss = v0.x * v0.x + v0.y * v0.y + v0.z * v0.z + v0.w * v0.w +
                       v1.x * v1.x + v1.y * v1.y + v1.z * v1.z + v1.w * v1.w;
            #pragma unroll
            for (int o = 16; o > 0; o >>= 1) ss += __shfl_xor(ss, o, 64);
            if ((tid & 31) == 0) sSQ[m] = ss;
            union { __bf16 o[8]; bf16x8 v; } cv;
            cv.o[0] = (__bf16)v0.x; cv.o[1] = (__bf16)v0.y;
            cv.o[2] = (__bf16)v0.z; cv.o[3] = (__bf16)v0.w;
            cv.o[4] = (__bf16)v1.x; cv.o[5] = (__bf16)v1.y;
            cv.o[6] = (__bf16)v1.z; cv.o[7] = (__bf16)v1.w;
            *(bf16x8*)(sFM + (m * 32 + kb * 4 + qq) * 8) = cv.v;
        }
        __syncthreads();
        int G0 = tid * 2;
        int kb0 = G0 >> 6, q0 = (G0 >> 4) & 3, m0 = G0 & 15;
        bf16x8 a = *(const bf16x8*)(sFM + (m0 * 32 + kb0 * 4 + q0) * 8);
        bf16x8 bgr = *(const bf16x8*)(sFM + ((m0 + 1) * 32 + kb0 * 4 + q0) * 8);
        *(bf16x8*)(out + ((size_t)g * 512 + G0) * 8) = a;
        *(bf16x8*)(out + ((size_t)g * 512 + G0 + 1) * 8) = bgr;
        if (tid < 16) sqout[g * 16 + tid] = sSQ[tid];
    } else {
        int idx = (blk - 2048) * 256 + tid;
        int m = idx & 15, q = (idx >> 4) & 3, kb = (idx >> 6) & 7, gn = idx >> 9;
        union { __bf16 o[8]; bf16x8 v; } cv;
        #pragma unroll
        for (int j = 0; j < 8; ++j)
            cv.o[j] = (__bf16)W[(size_t)(kb * 32 + q * 8 + j) * D_ + gn * 16 + m];
        *(bf16x8*)(WFM + (size_t)idx * 8) = cv.v;
    }
}

// ---------- K1: predW = pred x W, FM in / FM out (XCD-swizzled) ----------
__global__ __launch_bounds__(256, 2) void predw_mfma(
    const __bf16* __restrict__ predFM, const __bf16* __restrict__ WFM,
    const float* __restrict__ pred_mask, __bf16* __restrict__ pwFM) {
    __shared__ __align__(16) __bf16 sT[128 * 136];
    __shared__ int flag;
    int tid = threadIdx.x, lane = tid & 63, wid = tid >> 6;
    int wp = wid >> 1, wn = wid & 1;
    int id = blockIdx.x;
    int m0 = (((id >> 3) & 15) + (id & 7) * 16) * 128;
    int n0 = (id >> 7) * 128;
    if (tid == 0) flag = 0;
    __syncthreads();
    if (tid < 128) { if (pred_mask[m0 + tid] != 0.f) atomicOr(&flag, 1); }
    __syncthreads();
    if (!flag) return;

    const __bf16* bA = predFM + (size_t)(m0 / 16 + wp * 4) * 4096 + lane * 8;
    const __bf16* bB = WFM + (size_t)(n0 / 16 + wn * 4) * 4096 + lane * 8;
    f32x4 acc[4][4] = {};
    #pragma unroll
    for (int kb = 0; kb < 8; ++kb) {
        bf16x8 fA[4], fB[4];
        #pragma unroll
        for (int t = 0; t < 4; ++t) {
            fA[t] = *(const bf16x8*)(bA + (t * 8 + kb) * 512);
            fB[t] = *(const bf16x8*)(bB + (t * 8 + kb) * 512);
        }
        #pragma unroll
        for (int pt = 0; pt < 4; ++pt)
            #pragma unroll
            for (int st = 0; st < 4; ++st)
                acc[pt][st] = MFMA16(fA[pt], fB[st], acc[pt][st]);
    }
    int q = lane >> 4, cn = lane & 15;
    #pragma unroll
    for (int pt = 0; pt < 4; ++pt)
        #pragma unroll
        for (int st = 0; st < 4; ++st)
            #pragma unroll
            for (int r = 0; r < 4; ++r)
                sT[(wp * 64 + pt * 16 + q * 4 + r) * 136 + wn * 64 + st * 16 + cn] =
                    (__bf16)acc[pt][st][r];
    __syncthreads();
    #pragma unroll
    for (int i = 0; i < 8; ++i) {
        int idx = i * 256 + tid;
        int gl = idx >> 8, kbl = (idx >> 6) & 3, qq = (idx >> 4) & 3, mm = idx & 15;
        bf16x8 v = *(const bf16x8*)(sT + (gl * 16 + mm) * 136 + kbl * 32 + qq * 8);
        *(bf16x8*)(pwFM +
                   (((size_t)(m0 / 16 + gl) * 8 + n0 / 32 + kbl) * 64 + qq * 16 + mm) * 8) = v;
    }
}

// ---------- K2: fused T/G MFMA, 64p x 64s tiles, software-pipelined K-loop ----------
// wave wid owns rows [wid*16, wid*16+16) x all 64 cols; computes BOTH aT and aG;
// K-loop is manually double-buffered: kb+1's fragment loads are issued before
// kb's MFMAs consume the current buffer (keeps 6 loads in flight across MFMA).
// grid 8192: id = b + 8*px + 256*sy  (id&7 locks batch to XCD)
__global__ __launch_bounds__(256, 4) void fused_mfma(
    const __bf16* __restrict__ srcFM, const __bf16* __restrict__ predFM,
    const __bf16* __restrict__ pwFM,
    const float* __restrict__ src_mask, const float* __restrict__ pred_mask,
    const float* __restrict__ src_sq, const float* __restrict__ pred_sq,
    float* __restrict__ m_part, float* __restrict__ l_part,
    float* __restrict__ w_part, float* __restrict__ Sarr,
    unsigned int* __restrict__ counter) {
    __shared__ float sPM[64], sPSQ[64], sSM[64], sSSQ[64];
    __shared__ int flg[4];  // 0 anyValidP, 1 anyInvalidP, 2 anyValidS, 3 anyInvalidS
    int tid = threadIdx.x, lane = tid & 63, wid = tid >> 6;
    int id = blockIdx.x;
    int b = id & 7, px = (id >> 3) & 31, sy = id >> 8;  // sy 0..31
    int p0 = px * 64;

    if (id == 0) {  // init cross-kernel accumulators for combine (runs after us)
        if (tid == 0) *counter = 0u;
        if (tid < 24) Sarr[tid] = 0.f;
    }
    if (tid < 4) flg[tid] = 0;
    __syncthreads();
    if (tid < 64) {
        float v = pred_mask[b * L_ + p0 + tid];
        sPM[tid] = v;
        sPSQ[tid] = pred_sq[b * L_ + p0 + tid];
        atomicOr(&flg[(v != 0.f) ? 0 : 1], 1);
    } else if (tid < 128) {
        int t = tid - 64;
        float v = src_mask[b * L_ + sy * 64 + t];
        sSM[t] = v;
        sSSQ[t] = src_sq[b * L_ + sy * 64 + t];
        atomicOr(&flg[(v != 0.f) ? 2 : 3], 1);
    }
    __syncthreads();
    const bool anyVP = flg[0] != 0, anyIP = flg[1] != 0, anyVS = flg[2] != 0;
    const bool doT = anyVP && anyVS;
    const bool doG = anyVS || anyIP;
    if (!doG) {
        // all p valid & all s masked: strip is zero-weighted vs any real strip
        if (tid < 64) {
            size_t o = ((size_t)(b * L_ + p0 + tid)) * NSTRIP + sy;
            m_part[o] = NEG_INF_V; l_part[o] = 64.f; w_part[o] = 0.f;
        }
        return;
    }

    const __bf16* bS = srcFM + ((size_t)(b * 128 + sy * 4)) * 4096 + lane * 8;
    const __bf16* bP = predFM + ((size_t)(b * 128 + px * 4 + wid)) * 4096 + lane * 8;
    const __bf16* bW = pwFM + ((size_t)(b * 128 + px * 4 + wid)) * 4096 + lane * 8;

    f32x4 aT[4] = {};
    f32x4 aG[4] = {};
    if (doT) {
        bf16x8 cP, cW, cB[4], nP, nW, nB[4];
        cP = *(const bf16x8*)(bP);
        cW = *(const bf16x8*)(bW);
        #pragma unroll
        for (int t = 0; t < 4; ++t) cB[t] = *(const bf16x8*)(bS + t * 8 * 512);
        #pragma unroll
        for (int kb = 0; kb < 8; ++kb) {
            if (kb < 7) {
                nP = *(const bf16x8*)(bP + (kb + 1) * 512);
                nW = *(const bf16x8*)(bW + (kb + 1) * 512);
                #pragma unroll
                for (int t = 0; t < 4; ++t)
                    nB[t] = *(const bf16x8*)(bS + (t * 8 + kb + 1) * 512);
            }
            #pragma unroll
            for (int t = 0; t < 4; ++t) {
                aG[t] = MFMA16(cP, cB[t], aG[t]);
                aT[t] = MFMA16(cW, cB[t], aT[t]);
            }
            cP = nP; cW = nW;
            #pragma unroll
            for (int t = 0; t < 4; ++t) cB[t] = nB[t];
        }
    } else {
        bf16x8 cP, cB[4], nP, nB[4];
        cP = *(const bf16x8*)(bP);
        #pragma unroll
        for (int t = 0; t < 4; ++t) cB[t] = *(const bf16x8*)(bS + t * 8 * 512);
        #pragma unroll
        for (int kb = 0; kb < 8; ++kb) {
            if (kb < 7) {
                nP = *(const bf16x8*)(bP + (kb + 1) * 512);
                #pragma unroll
                for (int t = 0; t < 4; ++t)
                    nB[t] = *(const bf16x8*)(bS + (t * 8 + kb + 1) * 512);
            }
            #pragma unroll
            for (int t = 0; t < 4; ++t)
                aG[t] = MFMA16(cP, cB[t], aG[t]);
            cP = nP;
            #pragma unroll
            for (int t = 0; t < 4; ++t) cB[t] = nB[t];
        }
    }

    // epilogue: element (row = wid*16 + q*4 + r, col = t*16 + cn) = a[t][r]
    int q = lane >> 4, cn = lane & 15;
    float smv[4], sqv[4];
    #pragma unroll
    for (int t = 0; t < 4; ++t) {
        smv[t] = sSM[t * 16 + cn];
        sqv[t] = sSSQ[t * 16 + cn];
    }
    int rbase = wid * 16 + q * 4;
    #pragma unroll
    for (int r = 0; r < 4; ++r) {
        float pm = sPM[rbase + r], psq = sPSQ[rbase + r];
        float tv[4], cst[4];
        float tm = -1e30f;
        #pragma unroll
        for (int t = 0; t < 4; ++t) {
            cst[t] = __builtin_amdgcn_sqrtf(
                fmaxf(psq + sqv[t] - 2.f * aG[t][r], 0.f));
            float tt = doT ? aT[t][r] : NEG_INF_V;
            // pm==0: uniform row (tv=0 everywhere -> e=1, l=64, w=sum cost)
            tv[t] = (pm == 0.f) ? 0.f : (smv[t] != 0.f ? tt : NEG_INF_V);
            tm = fmaxf(tm, tv[t]);
        }
        #pragma unroll
        for (int o = 8; o > 0; o >>= 1) tm = fmaxf(tm, __shfl_xor(tm, o, 16));
        float l = 0.f, w = 0.f;
        #pragma unroll
        for (int t = 0; t < 4; ++t) {
            float e = __expf(tv[t] - tm);
            l += e;
            w = fmaf(e, cst[t], w);
        }
        #pragma unroll
        for (int o = 8; o > 0; o >>= 1) {
            l += __shfl_xor(l, o, 16);
            w += __shfl_xor(w, o, 16);
        }
        if (cn == 0) {
            size_t o = ((size_t)(b * L_ + p0 + rbase + r)) * NSTRIP + sy;
            m_part[o] = tm;
            l_part[o] = l;
            w_part[o] = w;
        }
    }
}

// ---------- K3: combine strips -> per-batch atomic sums; last block finalizes ----------
__global__ __launch_bounds__(256) void combine_kernel(
    const float* __restrict__ m_part, const float* __restrict__ l_part,
    const float* __restrict__ w_part,
    const float* __restrict__ x_mask, const float* __restrict__ y_mask,
    float* __restrict__ Sarr, unsigned int* __restrict__ counter,
    float* __restrict__ out) {
    int tid = threadIdx.x;
    int r = blockIdx.x * 256 + tid;  // 64 blocks, 8 per batch
    int b = r >> 11;
    size_t base = (size_t)r * NSTRIP;
    float mm = -1e30f;
    #pragma unroll
    for (int s = 0; s < NSTRIP; ++s) mm = fmaxf(mm, m_part[base + s]);
    float l = 0.f, w = 0.f;
    #pragma unroll
    for (int s = 0; s < NSTRIP; ++s) {
        float e = __expf(m_part[base + s] - mm);
        l = fmaf(l_part[base + s], e, l);
        w = fmaf(w_part[base + s], e, w);
    }
    float sv = w / l;
    float n1 = y_mask[r], n2 = x_mask[r];
    __shared__ float red[3][256];
    red[0][tid] = sv; red[1][tid] = n1; red[2][tid] = n2;
    __syncthreads();
    for (int o = 128; o > 0; o >>= 1) {
        if (tid < o) {
            red[0][tid] += red[0][tid + o];
            red[1][tid] += red[1][tid + o];
            red[2][tid] += red[2][tid + o];
        }
        __syncthreads();
    }
    __shared__ int isLast;
    if (tid == 0) {
        atomicAdd(&Sarr[b], red[0][0]);
        atomicAdd(&Sarr[8 + b], red[1][0]);
        atomicAdd(&Sarr[16 + b], red[2][0]);
        __threadfence();
        isLast = (atomicAdd(counter, 1u) == 63u) ? 1 : 0;
    }
    __syncthreads();
    if (isLast) {
        __shared__ float fb[24];
        if (tid < 24) fb[tid] = atomicAdd(&Sarr[tid], 0.f);  // coherent read
        __syncthreads();
        if (tid == 0) {
            float ss = 0.f, si = 0.f;
            for (int bb = 0; bb < B_; bb++) {
                ss += fb[bb];
                si += 1.0f / (fb[8 + bb] * fb[16 + bb]);
            }
            out[0] = ss * si / (float)(B_ * B_);  // LAMBDA_W = 1.0
        }
    }
}

extern "C" void kernel_launch(void* const* d_in, const int* in_sizes, int n_in,
                              void* d_out, int out_size, void* d_ws, size_t ws_size,
                              hipStream_t stream) {
    const float* h_x = (const float*)d_in[0];     // src
    const float* h_y = (const float*)d_in[1];     // pred
    const float* x_mask = (const float*)d_in[2];  // src_mask
    const float* y_mask = (const float*)d_in[3];  // pred_mask
    const float* W = (const float*)d_in[4];

    char* w8 = (char*)d_ws;
    const size_t BLD2 = (size_t)B_ * L_ * D_ * 2;  // 8 MB
    __bf16* srcFM = (__bf16*)w8;
    __bf16* predFM = (__bf16*)(w8 + BLD2);
    __bf16* pwFM = (__bf16*)(w8 + 2 * BLD2);
    __bf16* WFM = (__bf16*)(w8 + 3 * BLD2);                   // 128 KB
    float* src_sq = (float*)(w8 + 3 * BLD2 + (1 << 17));      // 64 KB
    float* pred_sq = (float*)(w8 + 3 * BLD2 + (1 << 17) + (1 << 16));
    char* pbase = w8 + 3 * BLD2 + (1 << 17) + (1 << 17);
    const size_t PSZ = (size_t)B_ * L_ * NSTRIP * 4;          // 2 MB each
    float* m_part = (float*)pbase;
    float* l_part = (float*)(pbase + PSZ);
    float* w_part = (float*)(pbase + 2 * PSZ);
    float* Sarr = (float*)(pbase + 3 * PSZ);                  // 24 floats
    unsigned int* counter = (unsigned int*)(pbase + 3 * PSZ + 128);

    convert_kernel<<<2080, 256, 0, stream>>>(h_x, h_y, W, srcFM, predFM, WFM,
                                             src_sq, pred_sq);
    predw_mfma<<<256, 256, 0, stream>>>(predFM, WFM, y_mask, pwFM);
    fused_mfma<<<8192, 256, 0, stream>>>(
        srcFM, predFM, pwFM, x_mask, y_mask, src_sq, pred_sq,
        m_part, l_part, w_part, Sarr, counter);
    combine_kernel<<<B_ * L_ / 256, 256, 0, stream>>>(
        m_part, l_part, w_part, x_mask, y_mask, Sarr, counter, (float*)d_out);
}

// Round 12
// 140.796 us; speedup vs baseline: 4.3659x; 1.0396x over previous
//
#include <hip/hip_runtime.h>
#include <math.h>
#include <stdint.h>

#define B_ 8
#define L_ 2048
#define D_ 256
#define NEG_INF_V (-1e10f)
#define NSTRIP 32

typedef __bf16 bf16x8 __attribute__((ext_vector_type(8)));
typedef float f32x4 __attribute__((ext_vector_type(4)));

#define MFMA16(a, b, c) __builtin_amdgcn_mfma_f32_16x16x32_bf16((a), (b), (c), 0, 0, 0)

// Fragment-major (FM) layout for a [rows x 256] bf16 matrix:
// granule index = ((G * 8 + kb) * 64 + q * 16 + m) ; granule = 16B = 8 bf16
// holds M[G*16 + m][kb*32 + q*8 .. +8).  G = absolute row/16.
// A wave (lane = q*16+m) loads frag (G_tile, kb) as one coalesced 1KB segment.

// ---------- K0: fp32 -> bf16 FM transform (coalesced) + row sumsq + W FM ----------
__global__ __launch_bounds__(256) void convert_kernel(
    const float* __restrict__ x, const float* __restrict__ y,
    const float* __restrict__ W,
    __bf16* __restrict__ srcFM, __bf16* __restrict__ predFM,
    __bf16* __restrict__ WFM,
    float* __restrict__ src_sq, float* __restrict__ pred_sq) {
    int tid = threadIdx.x;
    int blk = blockIdx.x;
    if (blk < 2048) {
        const float* in = (blk < 1024) ? x : y;
        __bf16* out = (blk < 1024) ? srcFM : predFM;
        float* sqout = (blk < 1024) ? src_sq : pred_sq;
        int g = blk & 1023;  // row-group (16 rows)
        __shared__ __align__(16) __bf16 sFM[512 * 8];
        __shared__ float sSQ[16];
        int kb = (tid & 31) >> 2, qq = tid & 3;
        #pragma unroll
        for (int pass = 0; pass < 2; ++pass) {
            int m = pass * 8 + (tid >> 5);
            const float* p = in + ((size_t)g * 16 + m) * D_ + (tid & 31) * 8;
            float4 v0 = *(const float4*)p;
            float4 v1 = *(const float4*)(p + 4);
            float ss = v0.x * v0.x + v0.y * v0.y + v0.z * v0.z + v0.w * v0.w +
                       v1.x * v1.x + v1.y * v1.y + v1.z * v1.z + v1.w * v1.w;
            #pragma unroll
            for (int o = 16; o > 0; o >>= 1) ss += __shfl_xor(ss, o, 64);
            if ((tid & 31) == 0) sSQ[m] = ss;
            union { __bf16 o[8]; bf16x8 v; } cv;
            cv.o[0] = (__bf16)v0.x; cv.o[1] = (__bf16)v0.y;
            cv.o[2] = (__bf16)v0.z; cv.o[3] = (__bf16)v0.w;
            cv.o[4] = (__bf16)v1.x; cv.o[5] = (__bf16)v1.y;
            cv.o[6] = (__bf16)v1.z; cv.o[7] = (__bf16)v1.w;
            *(bf16x8*)(sFM + (m * 32 + kb * 4 + qq) * 8) = cv.v;
        }
        __syncthreads();
        int G0 = tid * 2;
        int kb0 = G0 >> 6, q0 = (G0 >> 4) & 3, m0 = G0 & 15;
        bf16x8 a = *(const bf16x8*)(sFM + (m0 * 32 + kb0 * 4 + q0) * 8);
        bf16x8 bgr = *(const bf16x8*)(sFM + ((m0 + 1) * 32 + kb0 * 4 + q0) * 8);
        *(bf16x8*)(out + ((size_t)g * 512 + G0) * 8) = a;
        *(bf16x8*)(out + ((size_t)g * 512 + G0 + 1) * 8) = bgr;
        if (tid < 16) sqout[g * 16 + tid] = sSQ[tid];
    } else {
        int idx = (blk - 2048) * 256 + tid;
        int m = idx & 15, q = (idx >> 4) & 3, kb = (idx >> 6) & 7, gn = idx >> 9;
        union { __bf16 o[8]; bf16x8 v; } cv;
        #pragma unroll
        for (int j = 0; j < 8; ++j)
            cv.o[j] = (__bf16)W[(size_t)(kb * 32 + q * 8 + j) * D_ + gn * 16 + m];
        *(bf16x8*)(WFM + (size_t)idx * 8) = cv.v;
    }
}

// ---------- K1: predW = pred x W, FM in / FM out (XCD-swizzled) ----------
__global__ __launch_bounds__(256, 2) void predw_mfma(
    const __bf16* __restrict__ predFM, const __bf16* __restrict__ WFM,
    const float* __restrict__ pred_mask, __bf16* __restrict__ pwFM) {
    __shared__ __align__(16) __bf16 sT[128 * 136];
    __shared__ int flag;
    int tid = threadIdx.x, lane = tid & 63, wid = tid >> 6;
    int wp = wid >> 1, wn = wid & 1;
    int id = blockIdx.x;
    int m0 = (((id >> 3) & 15) + (id & 7) * 16) * 128;
    int n0 = (id >> 7) * 128;
    if (tid == 0) flag = 0;
    __syncthreads();
    if (tid < 128) { if (pred_mask[m0 + tid] != 0.f) atomicOr(&flag, 1); }
    __syncthreads();
    if (!flag) return;

    const __bf16* bA = predFM + (size_t)(m0 / 16 + wp * 4) * 4096 + lane * 8;
    const __bf16* bB = WFM + (size_t)(n0 / 16 + wn * 4) * 4096 + lane * 8;
    f32x4 acc[4][4] = {};
    #pragma unroll
    for (int kb = 0; kb < 8; ++kb) {
        bf16x8 fA[4], fB[4];
        #pragma unroll
        for (int t = 0; t < 4; ++t) {
            fA[t] = *(const bf16x8*)(bA + (t * 8 + kb) * 512);
            fB[t] = *(const bf16x8*)(bB + (t * 8 + kb) * 512);
        }
        #pragma unroll
        for (int pt = 0; pt < 4; ++pt)
            #pragma unroll
            for (int st = 0; st < 4; ++st)
                acc[pt][st] = MFMA16(fA[pt], fB[st], acc[pt][st]);
    }
    int q = lane >> 4, cn = lane & 15;
    #pragma unroll
    for (int pt = 0; pt < 4; ++pt)
        #pragma unroll
        for (int st = 0; st < 4; ++st)
            #pragma unroll
            for (int r = 0; r < 4; ++r)
                sT[(wp * 64 + pt * 16 + q * 4 + r) * 136 + wn * 64 + st * 16 + cn] =
                    (__bf16)acc[pt][st][r];
    __syncthreads();
    #pragma unroll
    for (int i = 0; i < 8; ++i) {
        int idx = i * 256 + tid;
        int gl = idx >> 8, kbl = (idx >> 6) & 3, qq = (idx >> 4) & 3, mm = idx & 15;
        bf16x8 v = *(const bf16x8*)(sT + (gl * 16 + mm) * 136 + kbl * 32 + qq * 8);
        *(bf16x8*)(pwFM +
                   (((size_t)(m0 / 16 + gl) * 8 + n0 / 32 + kbl) * 64 + qq * 16 + mm) * 8) = v;
    }
}

// ---------- K2: fused T/G MFMA, 64p x 64s tiles, 6 waves/SIMD occupancy ----------
// wave wid owns rows [wid*16, wid*16+16) x all 64 cols; computes BOTH aT and aG;
// epilogue reads T/G straight from the wave's own AGPRs. 80 unified regs ->
// __launch_bounds__(256,6) = 24 waves/CU so L2 latency is hidden by TLP.
// partials layout [sy][b*L+p]: full-cache-line writes (no RMW amplification).
// grid 8192: id = b + 8*px + 256*sy  (id&7 locks batch to XCD)
__global__ __launch_bounds__(256, 6) void fused_mfma(
    const __bf16* __restrict__ srcFM, const __bf16* __restrict__ predFM,
    const __bf16* __restrict__ pwFM,
    const float* __restrict__ src_mask, const float* __restrict__ pred_mask,
    const float* __restrict__ src_sq, const float* __restrict__ pred_sq,
    float* __restrict__ m_part, float* __restrict__ l_part,
    float* __restrict__ w_part, float* __restrict__ Sarr,
    unsigned int* __restrict__ counter) {
    __shared__ float sPM[64], sPSQ[64], sSM[64], sSSQ[64];
    __shared__ int flg[4];  // 0 anyValidP, 1 anyInvalidP, 2 anyValidS, 3 anyInvalidS
    int tid = threadIdx.x, lane = tid & 63, wid = tid >> 6;
    int id = blockIdx.x;
    int b = id & 7, px = (id >> 3) & 31, sy = id >> 8;  // sy 0..31
    int p0 = px * 64;

    if (id == 0) {  // init cross-kernel accumulators for combine (runs after us)
        if (tid == 0) *counter = 0u;
        if (tid < 24) Sarr[tid] = 0.f;
    }
    if (tid < 4) flg[tid] = 0;
    __syncthreads();
    if (tid < 64) {
        float v = pred_mask[b * L_ + p0 + tid];
        sPM[tid] = v;
        sPSQ[tid] = pred_sq[b * L_ + p0 + tid];
        atomicOr(&flg[(v != 0.f) ? 0 : 1], 1);
    } else if (tid < 128) {
        int t = tid - 64;
        float v = src_mask[b * L_ + sy * 64 + t];
        sSM[t] = v;
        sSSQ[t] = src_sq[b * L_ + sy * 64 + t];
        atomicOr(&flg[(v != 0.f) ? 2 : 3], 1);
    }
    __syncthreads();
    const bool anyVP = flg[0] != 0, anyIP = flg[1] != 0, anyVS = flg[2] != 0;
    const bool doT = anyVP && anyVS;
    const bool doG = anyVS || anyIP;
    if (!doG) {
        // all p valid & all s masked: strip is zero-weighted vs any real strip
        if (tid < 64) {
            size_t o = (size_t)sy * (B_ * L_) + b * L_ + p0 + tid;
            m_part[o] = NEG_INF_V; l_part[o] = 64.f; w_part[o] = 0.f;
        }
        return;
    }

    const __bf16* bS = srcFM + ((size_t)(b * 128 + sy * 4)) * 4096 + lane * 8;
    const __bf16* bP = predFM + ((size_t)(b * 128 + px * 4 + wid)) * 4096 + lane * 8;
    const __bf16* bW = pwFM + ((size_t)(b * 128 + px * 4 + wid)) * 4096 + lane * 8;

    f32x4 aT[4] = {};
    f32x4 aG[4] = {};
    if (doT) {
        #pragma unroll
        for (int kb = 0; kb < 8; ++kb) {
            bf16x8 fP = *(const bf16x8*)(bP + kb * 512);
            bf16x8 fW = *(const bf16x8*)(bW + kb * 512);
            bf16x8 fB[4];
            #pragma unroll
            for (int t = 0; t < 4; ++t)
                fB[t] = *(const bf16x8*)(bS + (t * 8 + kb) * 512);
            #pragma unroll
            for (int t = 0; t < 4; ++t) {
                aG[t] = MFMA16(fP, fB[t], aG[t]);
                aT[t] = MFMA16(fW, fB[t], aT[t]);
            }
        }
    } else {
        #pragma unroll
        for (int kb = 0; kb < 8; ++kb) {
            bf16x8 fP = *(const bf16x8*)(bP + kb * 512);
            bf16x8 fB[4];
            #pragma unroll
            for (int t = 0; t < 4; ++t)
                fB[t] = *(const bf16x8*)(bS + (t * 8 + kb) * 512);
            #pragma unroll
            for (int t = 0; t < 4; ++t)
                aG[t] = MFMA16(fP, fB[t], aG[t]);
        }
    }

    // epilogue: element (row = wid*16 + q*4 + r, col = t*16 + cn) = a[t][r]
    int q = lane >> 4, cn = lane & 15;
    float smv[4], sqv[4];
    #pragma unroll
    for (int t = 0; t < 4; ++t) {
        smv[t] = sSM[t * 16 + cn];
        sqv[t] = sSSQ[t * 16 + cn];
    }
    int rbase = wid * 16 + q * 4;
    #pragma unroll
    for (int r = 0; r < 4; ++r) {
        float pm = sPM[rbase + r], psq = sPSQ[rbase + r];
        float tv[4], cst[4];
        float tm = -1e30f;
        #pragma unroll
        for (int t = 0; t < 4; ++t) {
            cst[t] = __builtin_amdgcn_sqrtf(
                fmaxf(psq + sqv[t] - 2.f * aG[t][r], 0.f));
            float tt = doT ? aT[t][r] : NEG_INF_V;
            // pm==0: uniform row (tv=0 everywhere -> e=1, l=64, w=sum cost)
            tv[t] = (pm == 0.f) ? 0.f : (smv[t] != 0.f ? tt : NEG_INF_V);
            tm = fmaxf(tm, tv[t]);
        }
        #pragma unroll
        for (int o = 8; o > 0; o >>= 1) tm = fmaxf(tm, __shfl_xor(tm, o, 16));
        float l = 0.f, w = 0.f;
        #pragma unroll
        for (int t = 0; t < 4; ++t) {
            float e = __expf(tv[t] - tm);
            l += e;
            w = fmaf(e, cst[t], w);
        }
        #pragma unroll
        for (int o = 8; o > 0; o >>= 1) {
            l += __shfl_xor(l, o, 16);
            w += __shfl_xor(w, o, 16);
        }
        if (cn == 0) {
            size_t o = (size_t)sy * (B_ * L_) + b * L_ + p0 + rbase + r;
            m_part[o] = tm;
            l_part[o] = l;
            w_part[o] = w;
        }
    }
}

// ---------- K3: combine strips -> per-batch atomic sums; last block finalizes ----------
__global__ __launch_bounds__(256) void combine_kernel(
    const float* __restrict__ m_part, const float* __restrict__ l_part,
    const float* __restrict__ w_part,
    const float* __restrict__ x_mask, const float* __restrict__ y_mask,
    float* __restrict__ Sarr, unsigned int* __restrict__ counter,
    float* __restrict__ out) {
    int tid = threadIdx.x;
    int r = blockIdx.x * 256 + tid;  // 64 blocks, 8 per batch
    int b = r >> 11;
    float mm = -1e30f;
    #pragma unroll
    for (int s = 0; s < NSTRIP; ++s) mm = fmaxf(mm, m_part[(size_t)s * (B_ * L_) + r]);
    float l = 0.f, w = 0.f;
    #pragma unroll
    for (int s = 0; s < NSTRIP; ++s) {
        size_t o = (size_t)s * (B_ * L_) + r;
        float e = __expf(m_part[o] - mm);
        l = fmaf(l_part[o], e, l);
        w = fmaf(w_part[o], e, w);
    }
    float sv = w / l;
    float n1 = y_mask[r], n2 = x_mask[r];
    __shared__ float red[3][256];
    red[0][tid] = sv; red[1][tid] = n1; red[2][tid] = n2;
    __syncthreads();
    for (int o = 128; o > 0; o >>= 1) {
        if (tid < o) {
            red[0][tid] += red[0][tid + o];
            red[1][tid] += red[1][tid + o];
            red[2][tid] += red[2][tid + o];
        }
        __syncthreads();
    }
    __shared__ int isLast;
    if (tid == 0) {
        atomicAdd(&Sarr[b], red[0][0]);
        atomicAdd(&Sarr[8 + b], red[1][0]);
        atomicAdd(&Sarr[16 + b], red[2][0]);
        __threadfence();
        isLast = (atomicAdd(counter, 1u) == 63u) ? 1 : 0;
    }
    __syncthreads();
    if (isLast) {
        __shared__ float fb[24];
        if (tid < 24) fb[tid] = atomicAdd(&Sarr[tid], 0.f);  // coherent read
        __syncthreads();
        if (tid == 0) {
            float ss = 0.f, si = 0.f;
            for (int bb = 0; bb < B_; bb++) {
                ss += fb[bb];
                si += 1.0f / (fb[8 + bb] * fb[16 + bb]);
            }
            out[0] = ss * si / (float)(B_ * B_);  // LAMBDA_W = 1.0
        }
    }
}

extern "C" void kernel_launch(void* const* d_in, const int* in_sizes, int n_in,
                              void* d_out, int out_size, void* d_ws, size_t ws_size,
                              hipStream_t stream) {
    const float* h_x = (const float*)d_in[0];     // src
    const float* h_y = (const float*)d_in[1];     // pred
    const float* x_mask = (const float*)d_in[2];  // src_mask
    const float* y_mask = (const float*)d_in[3];  // pred_mask
    const float* W = (const float*)d_in[4];

    char* w8 = (char*)d_ws;
    const size_t BLD2 = (size_t)B_ * L_ * D_ * 2;  // 8 MB
    __bf16* srcFM = (__bf16*)w8;
    __bf16* predFM = (__bf16*)(w8 + BLD2);
    __bf16* pwFM = (__bf16*)(w8 + 2 * BLD2);
    __bf16* WFM = (__bf16*)(w8 + 3 * BLD2);                   // 128 KB
    float* src_sq = (float*)(w8 + 3 * BLD2 + (1 << 17));      // 64 KB
    float* pred_sq = (float*)(w8 + 3 * BLD2 + (1 << 17) + (1 << 16));
    char* pbase = w8 + 3 * BLD2 + (1 << 17) + (1 << 17);
    const size_t PSZ = (size_t)B_ * L_ * NSTRIP * 4;          // 2 MB each
    float* m_part = (float*)pbase;
    float* l_part = (float*)(pbase + PSZ);
    float* w_part = (float*)(pbase + 2 * PSZ);
    float* Sarr = (float*)(pbase + 3 * PSZ);                  // 24 floats
    unsigned int* counter = (unsigned int*)(pbase + 3 * PSZ + 128);

    convert_kernel<<<2080, 256, 0, stream>>>(h_x, h_y, W, srcFM, predFM, WFM,
                                             src_sq, pred_sq);
    predw_mfma<<<256, 256, 0, stream>>>(predFM, WFM, y_mask, pwFM);
    fused_mfma<<<8192, 256, 0, stream>>>(
        srcFM, predFM, pwFM, x_mask, y_mask, src_sq, pred_sq,
        m_part, l_part, w_part, Sarr, counter);
    combine_kernel<<<B_ * L_ / 256, 256, 0, stream>>>(
        m_part, l_part, w_part, x_mask, y_mask, Sarr, counter, (float*)d_out);
}